// Round 1
// baseline (256.930 us; speedup 1.0000x reference)
//
#include <hip/hip_runtime.h>
#include <hip/hip_bf16.h>
#include <hip/hip_fp16.h>

// EGATConv: GATConv(heads=1) with edge features. N=40000, E=640000,
// DIN=C=128, EDIM=32, fp32 in/out.
//
// Round-6 structure:
//  - ranks precomputed in gemm_h's fused count loop (atomic-return hidden
//    under GEMM); edge_fill places records at offs[dn]+rank[e] with NO
//    atomics (R5 edge_fill: 56us, VALU 3% -> atomic-return latency chain)
//  - dinfo[n] = {a_dst[n], bits(offs[n])}: one random 8B read instead of two 4B
//  - edge_fill: 4 edges/thread, batched independent loads (4x MLP)
//  - h stored bf16; 4-byte edge records (src u16 | fp16 ex)
//  - softmax without segment-max shift (alpha bounded, exp safe in fp32)

#define DIN 128
#define CCH 128
#define EDIM 32
#define XS_LD 68  // 64 k + 4 pad floats; 272 B row stride (16-B aligned)

__device__ __forceinline__ unsigned pack_bf2(float a, float b) {
    __hip_bfloat16 x = __float2bfloat16(a);
    __hip_bfloat16 y = __float2bfloat16(b);
    unsigned short ux = *(unsigned short*)&x;
    unsigned short uy = *(unsigned short*)&y;
    return (unsigned)ux | ((unsigned)uy << 16);
}

// ---------- h = x @ W (bf16) + fused node logits + fused count&rank ----------
__global__ __launch_bounds__(256) void gemm_h(
    const float* __restrict__ x, const float* __restrict__ W,
    const float* __restrict__ att_src, const float* __restrict__ att_dst,
    const int* __restrict__ ei, unsigned* __restrict__ hb,
    float* __restrict__ a_src, float* __restrict__ a_dst,
    int* __restrict__ count, unsigned short* __restrict__ rank,
    int N, int E) {
    __shared__ float xs[64 * XS_LD];  // 17 KB   xs[r][k] (one k-half)
    __shared__ float wl[64 * CCH];    // 32 KB   wl[k][c] (one k-half)
    const int t = threadIdx.x;
    const int tx = t & 15;
    const int ty = t >> 4;
    const int row0 = blockIdx.x * 64;

    // fused degree count + per-edge rank (latency hidden under GEMM)
    {
        const int* eid = ei + E;
        const int stride = gridDim.x * 256;
        for (int e = blockIdx.x * 256 + t; e < E; e += stride) {
            int r = atomicAdd(&count[eid[e]], 1);
            rank[e] = (unsigned short)r;
        }
    }

    float acc[4][8];
#pragma unroll
    for (int r = 0; r < 4; ++r)
#pragma unroll
        for (int c = 0; c < 8; ++c) acc[r][c] = 0.0f;

    for (int kh = 0; kh < 2; ++kh) {
        __syncthreads();
        {
            const float4* xg = (const float4*)x;
#pragma unroll
            for (int i = 0; i < 4; ++i) {
                int j4 = t + 256 * i;
                int r = j4 >> 4;
                int k = (j4 & 15) * 4;
                float4 v = xg[(size_t)(row0 + r) * 32 + kh * 16 + (j4 & 15)];
                *(float4*)&xs[r * XS_LD + k] = v;
            }
        }
        {
            const float4* wg = (const float4*)W;
#pragma unroll
            for (int i = 0; i < 8; ++i) {
                int j4 = t + 256 * i;
                int k = j4 >> 5;
                int c4 = j4 & 31;
                float4 v = wg[(size_t)(kh * 64 + k) * 32 + c4];
                *(float4*)&wl[k * CCH + c4 * 4] = v;
            }
        }
        __syncthreads();

#pragma unroll 4
        for (int k4 = 0; k4 < 64; k4 += 4) {
            float xr[4][4];
#pragma unroll
            for (int r = 0; r < 4; ++r) {
                float4 v = *(const float4*)&xs[(ty * 4 + r) * XS_LD + k4];
                xr[r][0] = v.x; xr[r][1] = v.y; xr[r][2] = v.z; xr[r][3] = v.w;
            }
            float wr[4][8];
#pragma unroll
            for (int i = 0; i < 4; ++i) {
                float4 w0 = *(const float4*)&wl[(k4 + i) * CCH + tx * 8];
                float4 w1 = *(const float4*)&wl[(k4 + i) * CCH + tx * 8 + 4];
                wr[i][0] = w0.x; wr[i][1] = w0.y; wr[i][2] = w0.z; wr[i][3] = w0.w;
                wr[i][4] = w1.x; wr[i][5] = w1.y; wr[i][6] = w1.z; wr[i][7] = w1.w;
            }
#pragma unroll
            for (int i = 0; i < 4; ++i)
#pragma unroll
                for (int r = 0; r < 4; ++r)
#pragma unroll
                    for (int c = 0; c < 8; ++c)
                        acc[r][c] += xr[r][i] * wr[i][c];
        }
    }

    float asv[8], adv[8];
#pragma unroll
    for (int c = 0; c < 8; ++c) {
        asv[c] = att_src[tx * 8 + c];
        adv[c] = att_dst[tx * 8 + c];
    }
#pragma unroll
    for (int r = 0; r < 4; ++r) {
        const int row = row0 + ty * 4 + r;
        unsigned u0 = pack_bf2(acc[r][0], acc[r][1]);
        unsigned u1 = pack_bf2(acc[r][2], acc[r][3]);
        unsigned u2 = pack_bf2(acc[r][4], acc[r][5]);
        unsigned u3 = pack_bf2(acc[r][6], acc[r][7]);
        *(uint4*)&hb[(size_t)row * 64 + tx * 4] = make_uint4(u0, u1, u2, u3);
        float ps = 0.0f, pd = 0.0f;
#pragma unroll
        for (int c = 0; c < 8; ++c) {
            ps += acc[r][c] * asv[c];
            pd += acc[r][c] * adv[c];
        }
        ps += __shfl_down(ps, 8, 16);
        pd += __shfl_down(pd, 8, 16);
        ps += __shfl_down(ps, 4, 16);
        pd += __shfl_down(pd, 4, 16);
        ps += __shfl_down(ps, 2, 16);
        pd += __shfl_down(pd, 2, 16);
        ps += __shfl_down(ps, 1, 16);
        pd += __shfl_down(pd, 1, 16);
        if (tx == 0) {
            a_src[row] = ps;
            a_dst[row] = pd;
        }
    }
}

// ---------- scan phase 1: per-block sums of count (int4) ----------
__global__ __launch_bounds__(256) void scan_part(const int* __restrict__ count,
                                                 int* __restrict__ bsum, int N4) {
    int i4 = blockIdx.x * 256 + threadIdx.x;
    int s = 0;
    if (i4 < N4) {
        int4 vv = ((const int4*)count)[i4];
        s = vv.x + vv.y + vv.z + vv.w;
    }
#pragma unroll
    for (int off = 32; off; off >>= 1) s += __shfl_down(s, off);
    __shared__ int wsum[4];
    if ((threadIdx.x & 63) == 0) wsum[threadIdx.x >> 6] = s;
    __syncthreads();
    if (threadIdx.x == 0)
        bsum[blockIdx.x] = wsum[0] + wsum[1] + wsum[2] + wsum[3];
}

// ---------- scan phase 2: exclusive offs + dinfo = {a_dst, bits(offs)} ----------
__global__ __launch_bounds__(256) void scan_apply(
    const int* __restrict__ count, const int* __restrict__ bsum,
    const float* __restrict__ a_dst, int* __restrict__ offs,
    float2* __restrict__ dinfo, int N4) {
    __shared__ int s_boff;
    __shared__ int wt[4];
    if (threadIdx.x == 0) {
        int s = 0;
        for (int i = 0; i < (int)blockIdx.x; ++i) s += bsum[i];
        s_boff = s;
    }
    int i4 = blockIdx.x * 256 + threadIdx.x;
    int4 vv = make_int4(0, 0, 0, 0);
    if (i4 < N4) vv = ((const int4*)count)[i4];
    int s = vv.x + vv.y + vv.z + vv.w;
    int lane = threadIdx.x & 63, w = threadIdx.x >> 6;
    int inc = s;
#pragma unroll
    for (int off = 1; off < 64; off <<= 1) {
        int u = __shfl_up(inc, off);
        if (lane >= off) inc += u;
    }
    if (lane == 63) wt[w] = inc;
    __syncthreads();
    int woff = 0;
    for (int i = 0; i < w; ++i) woff += wt[i];
    int exd = s_boff + woff + inc - s;  // exclusive prefix
    if (i4 < N4) {
        int4 o;
        o.x = exd;
        o.y = exd + vv.x;
        o.z = exd + vv.x + vv.y;
        o.w = exd + vv.x + vv.y + vv.z;
        ((int4*)offs)[i4] = o;
        float4 ad = ((const float4*)a_dst)[i4];
        float4 d0 = make_float4(ad.x, __int_as_float(o.x),
                                ad.y, __int_as_float(o.y));
        float4 d1 = make_float4(ad.z, __int_as_float(o.z),
                                ad.w, __int_as_float(o.w));
        ((float4*)dinfo)[i4 * 2] = d0;
        ((float4*)dinfo)[i4 * 2 + 1] = d1;
    }
}

// ---------- edge pass: 4 edges/thread, no atomics, deterministic CSR slot ----------
__global__ __launch_bounds__(256) void edge_fill(
    const int* __restrict__ ei, const float* __restrict__ ea,
    const float* __restrict__ W_edge, const float* __restrict__ att_edge,
    const float* __restrict__ a_src, const float2* __restrict__ dinfo,
    const unsigned short* __restrict__ rank, unsigned* __restrict__ pairs,
    int E) {
    __shared__ float vpart[8][EDIM];
    __shared__ float vl[EDIM];
    const int t = threadIdx.x;
    {   // v = W_edge @ att_edge, all 256 threads cooperate
        int j = t & 31, seg = t >> 5;  // 8 segments x 16 k
        const float* wr = W_edge + j * CCH + seg * 16;
        const float* ar = att_edge + seg * 16;
        float p = 0.0f;
#pragma unroll
        for (int k = 0; k < 16; ++k) p += wr[k] * ar[k];
        vpart[seg][j] = p;
    }
    __syncthreads();
    if (t < EDIM) {
        float s = 0.0f;
#pragma unroll
        for (int i = 0; i < 8; ++i) s += vpart[i][t];
        vl[t] = s;
    }
    __syncthreads();

    const int base = blockIdx.x * 1024 + t;
    int eidx[4], sn[4], dn[4], rk[4];
    bool ok[4];
#pragma unroll
    for (int i = 0; i < 4; ++i) {
        eidx[i] = base + 256 * i;
        ok[i] = eidx[i] < E;
    }
#pragma unroll
    for (int i = 0; i < 4; ++i) {
        sn[i] = ok[i] ? ei[eidx[i]] : 0;
        dn[i] = ok[i] ? ei[E + eidx[i]] : 0;
    }
#pragma unroll
    for (int i = 0; i < 4; ++i) rk[i] = ok[i] ? (int)rank[eidx[i]] : 0;
    float asv[4];
    float2 di[4];
#pragma unroll
    for (int i = 0; i < 4; ++i) {
        asv[i] = a_src[sn[i]];
        di[i] = dinfo[dn[i]];
    }
    float dot[4];
#pragma unroll
    for (int i = 0; i < 4; ++i) {
        float s = 0.0f;
        if (ok[i]) {
            const float4* ea4 = (const float4*)(ea + (size_t)eidx[i] * EDIM);
#pragma unroll
            for (int j = 0; j < 8; ++j) {
                float4 q = ea4[j];
                s += q.x * vl[4 * j] + q.y * vl[4 * j + 1] +
                     q.z * vl[4 * j + 2] + q.w * vl[4 * j + 3];
            }
        }
        dot[i] = s;
    }
#pragma unroll
    for (int i = 0; i < 4; ++i) {
        if (!ok[i]) continue;
        float alpha = asv[i] + di[i].x + dot[i];
        alpha = alpha > 0.0f ? alpha : 0.2f * alpha;
        float ex = __expf(alpha);
        unsigned rec = (unsigned)(unsigned short)sn[i] |
                       ((unsigned)__half_as_ushort(__float2half(ex)) << 16);
        int p = __float_as_int(di[i].y) + rk[i];
        pairs[p] = rec;
    }
}

#define GATHER_EDGE(rec)                                                      \
    {                                                                         \
        unsigned q = hb[(size_t)((rec) & 0xffffu) * 64 + lane];               \
        float exv = __half2float(__ushort_as_half((unsigned short)((rec) >> 16))); \
        a0 += exv * __uint_as_float(q << 16);                                 \
        a1 += exv * __uint_as_float(q & 0xffff0000u);                         \
        sum += exv;                                                           \
    }

// ---------- gather: wave per node; out = sum(ex*h[src])/sum(ex) + bias ----------
__global__ __launch_bounds__(256) void gather_k(
    const int* __restrict__ count, const int* __restrict__ offs,
    const unsigned* __restrict__ pairs, const unsigned* __restrict__ hb,
    const float* __restrict__ bias, float* __restrict__ out, int N) {
    int n = blockIdx.x * 4 + (threadIdx.x >> 6);
    int lane = threadIdx.x & 63;
    if (n >= N) return;
    int cnt = count[n];
    int start = offs[n];
    float a0 = 0.0f, a1 = 0.0f, sum = 0.0f;
    int j = 0;
    int head = (4 - (start & 3)) & 3;
    if (head > cnt) head = cnt;
    for (; j < head; ++j) {
        unsigned r = pairs[start + j];
        GATHER_EDGE(r);
    }
    int nq = (cnt - j) >> 2;
    if (nq > 0) {
        const uint4* pp4 = (const uint4*)(pairs + start + j);
        uint4 cur = pp4[0];
        for (int g = 0; g + 1 < nq; ++g) {
            uint4 nxt = pp4[g + 1];
            unsigned q0 = hb[(size_t)(cur.x & 0xffffu) * 64 + lane];
            unsigned q1 = hb[(size_t)(cur.y & 0xffffu) * 64 + lane];
            unsigned q2 = hb[(size_t)(cur.z & 0xffffu) * 64 + lane];
            unsigned q3 = hb[(size_t)(cur.w & 0xffffu) * 64 + lane];
            float e0 = __half2float(__ushort_as_half((unsigned short)(cur.x >> 16)));
            float e1 = __half2float(__ushort_as_half((unsigned short)(cur.y >> 16)));
            float e2 = __half2float(__ushort_as_half((unsigned short)(cur.z >> 16)));
            float e3 = __half2float(__ushort_as_half((unsigned short)(cur.w >> 16)));
            a0 += e0 * __uint_as_float(q0 << 16);
            a1 += e0 * __uint_as_float(q0 & 0xffff0000u);
            a0 += e1 * __uint_as_float(q1 << 16);
            a1 += e1 * __uint_as_float(q1 & 0xffff0000u);
            a0 += e2 * __uint_as_float(q2 << 16);
            a1 += e2 * __uint_as_float(q2 & 0xffff0000u);
            a0 += e3 * __uint_as_float(q3 << 16);
            a1 += e3 * __uint_as_float(q3 & 0xffff0000u);
            sum += (e0 + e1) + (e2 + e3);
            cur = nxt;
        }
        {
            unsigned q0 = hb[(size_t)(cur.x & 0xffffu) * 64 + lane];
            unsigned q1 = hb[(size_t)(cur.y & 0xffffu) * 64 + lane];
            unsigned q2 = hb[(size_t)(cur.z & 0xffffu) * 64 + lane];
            unsigned q3 = hb[(size_t)(cur.w & 0xffffu) * 64 + lane];
            float e0 = __half2float(__ushort_as_half((unsigned short)(cur.x >> 16)));
            float e1 = __half2float(__ushort_as_half((unsigned short)(cur.y >> 16)));
            float e2 = __half2float(__ushort_as_half((unsigned short)(cur.z >> 16)));
            float e3 = __half2float(__ushort_as_half((unsigned short)(cur.w >> 16)));
            a0 += e0 * __uint_as_float(q0 << 16);
            a1 += e0 * __uint_as_float(q0 & 0xffff0000u);
            a0 += e1 * __uint_as_float(q1 << 16);
            a1 += e1 * __uint_as_float(q1 & 0xffff0000u);
            a0 += e2 * __uint_as_float(q2 << 16);
            a1 += e2 * __uint_as_float(q2 & 0xffff0000u);
            a0 += e3 * __uint_as_float(q3 << 16);
            a1 += e3 * __uint_as_float(q3 & 0xffff0000u);
            sum += (e0 + e1) + (e2 + e3);
        }
        j += nq * 4;
    }
    for (; j < cnt; ++j) {
        unsigned r = pairs[start + j];
        GATHER_EDGE(r);
    }
    float inv = 1.0f / (sum + 1e-16f);
    float2 bv = *(const float2*)&bias[2 * lane];
    float2 o;
    o.x = a0 * inv + bv.x;
    o.y = a1 * inv + bv.y;
    *(float2*)&out[(size_t)n * CCH + 2 * lane] = o;
}

extern "C" void kernel_launch(void* const* d_in, const int* in_sizes, int n_in,
                              void* d_out, int out_size, void* d_ws, size_t ws_size,
                              hipStream_t stream) {
    const float* x        = (const float*)d_in[0];
    const int*   ei       = (const int*)d_in[1];
    const float* ea       = (const float*)d_in[2];
    const float* W        = (const float*)d_in[3];
    const float* W_edge   = (const float*)d_in[4];
    const float* att_src  = (const float*)d_in[5];
    const float* att_dst  = (const float*)d_in[6];
    const float* att_edge = (const float*)d_in[7];
    const float* bias     = (const float*)d_in[8];
    float* out = (float*)d_out;

    const int N = in_sizes[0] / DIN;   // 40000
    const int E = in_sizes[2] / EDIM;  // 640000
    const int N4 = N / 4;              // 10000
    const int NB = (N4 + 255) / 256;   // 40 scan blocks

    // workspace layout (all offsets 16-B aligned for these sizes)
    char* ws = (char*)d_ws;
    unsigned*       hb    = (unsigned*)ws;                         // N*64 u32
    unsigned*       pairs = (unsigned*)(ws + (size_t)N * 64 * 4);  // E u32
    unsigned short* rank  = (unsigned short*)(pairs + E);          // E u16
    float*  a_src = (float*)((char*)rank + (size_t)E * 2);         // N f
    float*  a_dst = a_src + N;                                     // N f
    float2* dinfo = (float2*)(a_dst + N);                          // N float2
    int*    count = (int*)(dinfo + N);                             // N i
    int*    offs  = count + N;                                     // N i
    int*    bsum  = offs + N;                                      // NB i

    hipMemsetAsync(count, 0, (size_t)N * sizeof(int), stream);

    gemm_h<<<N / 64, 256, 0, stream>>>(x, W, att_src, att_dst, ei, hb,
                                       a_src, a_dst, count, rank, N, E);
    scan_part<<<NB, 256, 0, stream>>>(count, bsum, N4);
    scan_apply<<<NB, 256, 0, stream>>>(count, bsum, a_dst, offs, dinfo, N4);
    edge_fill<<<(E + 1023) / 1024, 256, 0, stream>>>(ei, ea, W_edge, att_edge,
                                                     a_src, dinfo, rank, pairs, E);
    gather_k<<<(N + 3) / 4, 256, 0, stream>>>(count, offs, pairs, hb, bias, out, N);
}

// Round 3
// 238.904 us; speedup vs baseline: 1.0755x; 1.0755x over previous
//
#include <hip/hip_runtime.h>
#include <hip/hip_bf16.h>
#include <hip/hip_fp16.h>

// EGATConv: GATConv(heads=1) with edge features. N=40000, E=640000,
// DIN=C=128, EDIM=32, fp32 in/out.
//
// Round-8 structure (R6 + MFMA gemm + ea-stream fusion, ws kept < 16 MiB):
//  - gemm_h rewritten as MFMA bf16x2-split GEMM (3 passes: hh+hl+lh ~ fp32
//    accuracy). Computes D = W^T x^T so each lane owns 4 consecutive output
//    channels of one row -> h bf16 pack needs no cross-lane shuffle.
//    LDS 50KB->32KB, occupancy 2.4 -> ~4-5 blocks/CU.
//  - a_edge = ea @ (W_edge @ att_edge) computed INSIDE gemm_h (82 MB stream
//    hides in gemm's latency stalls; gemm_h was at 10% HBM).
//  - erec[e] u32 = rank u16 (lo) | fp16 a_edge (hi). Two independent u16
//    stores from different threads (no race). Keeps workspace at 16.32 MB
//    (R1's separate f32 a_edge was 17.6 MB -> suspected 16 MiB ws overflow).
//  - rest identical: fused count/rank atomics under gemm, scan, no-atomic
//    edge_fill CSR placement, wave-per-node gather, bf16 h, fp16 ex records.

#define DIN 128
#define CCH 128
#define EDIM 32
#define LDK 40  // padded k stride in ushorts (80 B rows, 16-B aligned frags)

typedef __attribute__((ext_vector_type(8))) short short8v;
typedef __attribute__((ext_vector_type(4))) float f32x4;

__device__ __forceinline__ unsigned short f2b(float v) {
    __hip_bfloat16 b = __float2bfloat16(v);
    return *(unsigned short*)&b;
}
__device__ __forceinline__ float b2f(unsigned short u) {
    return __uint_as_float((unsigned)u << 16);
}
__device__ __forceinline__ unsigned pack_bf2(float a, float b) {
    return (unsigned)f2b(a) | ((unsigned)f2b(b) << 16);
}

// ---------- h = x @ W (MFMA bf16x2) + node logits + count&rank + a_edge ----------
__global__ __launch_bounds__(256, 4) void gemm_h(
    const float* __restrict__ x, const float* __restrict__ W,
    const float* __restrict__ att_src, const float* __restrict__ att_dst,
    const float* __restrict__ W_edge, const float* __restrict__ att_edge,
    const int* __restrict__ ei, const float* __restrict__ ea,
    unsigned* __restrict__ hb, float* __restrict__ a_src,
    float* __restrict__ a_dst, unsigned* __restrict__ erec,
    int* __restrict__ count, int N, int E) {
    __shared__ unsigned short xs_h[64 * LDK];   // x quarter, hi plane  [r][k]
    __shared__ unsigned short xs_l[64 * LDK];   // lo plane
    __shared__ unsigned short wt_h[128 * LDK];  // W^T quarter, hi      [c][k]
    __shared__ unsigned short wt_l[128 * LDK];  // lo plane
    __shared__ float vpart[8][EDIM];
    __shared__ float vl[EDIM];

    const int t = threadIdx.x;
    const int ln = t & 63;
    const int wv = t >> 6;
    const int lr = ln & 15;  // B col (node row) / A row (channel) in fragment
    const int lk = ln >> 4;  // k-group
    const int row0 = blockIdx.x * 64;

    // fused degree count + per-edge rank (latency hidden under GEMM)
    {
        const int* eid = ei + E;
        const int stride = gridDim.x * 256;
        for (int e = blockIdx.x * 256 + t; e < E; e += stride) {
            int r = atomicAdd(&count[eid[e]], 1);
            ((unsigned short*)&erec[e])[0] = (unsigned short)r;  // lo half
        }
    }

    // vl = W_edge @ att_edge  (32 values, cooperative)
    {
        int j = t & 31, seg = t >> 5;  // 8 segments x 16 k
        const float* wr = W_edge + j * CCH + seg * 16;
        const float* ar = att_edge + seg * 16;
        float p = 0.0f;
#pragma unroll
        for (int k = 0; k < 16; ++k) p += wr[k] * ar[k];
        vpart[seg][j] = p;
    }
    __syncthreads();
    if (t < EDIM) {
        float s = 0.0f;
#pragma unroll
        for (int i = 0; i < 8; ++i) s += vpart[i][t];
        vl[t] = s;
    }
    // (first q-loop barrier makes vl visible before its use at the end)

    f32x4 acc[8];
#pragma unroll
    for (int cf = 0; cf < 8; ++cf) acc[cf] = (f32x4)(0.0f);

    const float4* x4 = (const float4*)x;
    const float4* W4 = (const float4*)W;

    for (int q = 0; q < 4; ++q) {  // K quarters of 32
        __syncthreads();
        // stage x quarter: 64 rows x 32 k, fp32 -> bf16 hi/lo
#pragma unroll
        for (int i = 0; i < 2; ++i) {
            int j4 = t + 256 * i;
            int r = j4 >> 3;
            int f4 = j4 & 7;
            float4 v = x4[(size_t)(row0 + r) * 32 + q * 8 + f4];
            float vv[4] = {v.x, v.y, v.z, v.w};
            unsigned short h[4], l[4];
#pragma unroll
            for (int m = 0; m < 4; ++m) {
                h[m] = f2b(vv[m]);
                l[m] = f2b(vv[m] - b2f(h[m]));
            }
            uint2 uh = make_uint2((unsigned)h[0] | ((unsigned)h[1] << 16),
                                  (unsigned)h[2] | ((unsigned)h[3] << 16));
            uint2 ul = make_uint2((unsigned)l[0] | ((unsigned)l[1] << 16),
                                  (unsigned)l[2] | ((unsigned)l[3] << 16));
            *(uint2*)&xs_h[r * LDK + f4 * 4] = uh;
            *(uint2*)&xs_l[r * LDK + f4 * 4] = ul;
        }
        // stage W^T quarter: 32 k x 128 c, transposed to [c][k] hi/lo
        {
            int kt = t >> 5;   // k base kt*4
            int ct = t & 31;   // c base ct*4
            float w4[4][4];
#pragma unroll
            for (int i = 0; i < 4; ++i) {
                float4 v = W4[(size_t)(q * 32 + kt * 4 + i) * 32 + ct];
                w4[i][0] = v.x; w4[i][1] = v.y; w4[i][2] = v.z; w4[i][3] = v.w;
            }
#pragma unroll
            for (int cc = 0; cc < 4; ++cc) {
                unsigned short h[4], l[4];
#pragma unroll
                for (int i = 0; i < 4; ++i) {
                    h[i] = f2b(w4[i][cc]);
                    l[i] = f2b(w4[i][cc] - b2f(h[i]));
                }
                uint2 uh = make_uint2((unsigned)h[0] | ((unsigned)h[1] << 16),
                                      (unsigned)h[2] | ((unsigned)h[3] << 16));
                uint2 ul = make_uint2((unsigned)l[0] | ((unsigned)l[1] << 16),
                                      (unsigned)l[2] | ((unsigned)l[3] << 16));
                int c = ct * 4 + cc;
                *(uint2*)&wt_h[c * LDK + kt * 4] = uh;
                *(uint2*)&wt_l[c * LDK + kt * 4] = ul;
            }
        }
        __syncthreads();

        // one K=32 MFMA step per quarter
        short8v bh = *(const short8v*)&xs_h[(wv * 16 + lr) * LDK + lk * 8];
        short8v bl = *(const short8v*)&xs_l[(wv * 16 + lr) * LDK + lk * 8];
#pragma unroll
        for (int cf = 0; cf < 8; ++cf) {
            short8v ah = *(const short8v*)&wt_h[(cf * 16 + lr) * LDK + lk * 8];
            short8v al = *(const short8v*)&wt_l[(cf * 16 + lr) * LDK + lk * 8];
            acc[cf] = __builtin_amdgcn_mfma_f32_16x16x32_bf16(ah, bh, acc[cf], 0, 0, 0);
            acc[cf] = __builtin_amdgcn_mfma_f32_16x16x32_bf16(ah, bl, acc[cf], 0, 0, 0);
            acc[cf] = __builtin_amdgcn_mfma_f32_16x16x32_bf16(al, bh, acc[cf], 0, 0, 0);
        }
    }

    // outputs: lane holds h[row][c..c+3] for row=row0+wv*16+lr, c=cf*16+lk*4
    {
        const int row = row0 + wv * 16 + lr;
        float ps = 0.0f, pd = 0.0f;
#pragma unroll
        for (int cf = 0; cf < 8; ++cf) {
            int c0 = cf * 16 + lk * 4;
            float4 as4 = *(const float4*)&att_src[c0];
            float4 ad4 = *(const float4*)&att_dst[c0];
            ps += acc[cf][0] * as4.x + acc[cf][1] * as4.y +
                  acc[cf][2] * as4.z + acc[cf][3] * as4.w;
            pd += acc[cf][0] * ad4.x + acc[cf][1] * ad4.y +
                  acc[cf][2] * ad4.z + acc[cf][3] * ad4.w;
            uint2 u = make_uint2(pack_bf2(acc[cf][0], acc[cf][1]),
                                 pack_bf2(acc[cf][2], acc[cf][3]));
            *(uint2*)&hb[(size_t)row * 64 + cf * 8 + lk * 2] = u;
        }
        ps += __shfl_xor(ps, 16);
        ps += __shfl_xor(ps, 32);
        pd += __shfl_xor(pd, 16);
        pd += __shfl_xor(pd, 32);
        if (ln < 16) {
            a_src[row0 + wv * 16 + ln] = ps;
            a_dst[row0 + wv * 16 + ln] = pd;
        }
    }

    // a_edge stream: 1024 edges/block, ea row (128 B) dot vl -> fp16 hi half
    {
        float vlr[EDIM];
#pragma unroll
        for (int j = 0; j < EDIM; ++j) vlr[j] = vl[j];
        const float4* ea4 = (const float4*)ea;
        const int e0 = blockIdx.x * 1024 + t;
#pragma unroll
        for (int i = 0; i < 4; ++i) {
            int e = e0 + 256 * i;
            if (e < E) {
                float s = 0.0f;
#pragma unroll
                for (int j = 0; j < 8; ++j) {
                    float4 v = ea4[(size_t)e * 8 + j];
                    s += v.x * vlr[4 * j] + v.y * vlr[4 * j + 1] +
                         v.z * vlr[4 * j + 2] + v.w * vlr[4 * j + 3];
                }
                ((unsigned short*)&erec[e])[1] =
                    __half_as_ushort(__float2half(s));  // hi half
            }
        }
    }
}

// ---------- scan phase 1: per-block sums of count (int4) ----------
__global__ __launch_bounds__(256) void scan_part(const int* __restrict__ count,
                                                 int* __restrict__ bsum, int N4) {
    int i4 = blockIdx.x * 256 + threadIdx.x;
    int s = 0;
    if (i4 < N4) {
        int4 vv = ((const int4*)count)[i4];
        s = vv.x + vv.y + vv.z + vv.w;
    }
#pragma unroll
    for (int off = 32; off; off >>= 1) s += __shfl_down(s, off);
    __shared__ int wsum[4];
    if ((threadIdx.x & 63) == 0) wsum[threadIdx.x >> 6] = s;
    __syncthreads();
    if (threadIdx.x == 0)
        bsum[blockIdx.x] = wsum[0] + wsum[1] + wsum[2] + wsum[3];
}

// ---------- scan phase 2: exclusive offs + dinfo = {a_dst, bits(offs)} ----------
__global__ __launch_bounds__(256) void scan_apply(
    const int* __restrict__ count, const int* __restrict__ bsum,
    const float* __restrict__ a_dst, int* __restrict__ offs,
    float2* __restrict__ dinfo, int N4) {
    __shared__ int s_boff;
    __shared__ int wt[4];
    if (threadIdx.x == 0) {
        int s = 0;
        for (int i = 0; i < (int)blockIdx.x; ++i) s += bsum[i];
        s_boff = s;
    }
    int i4 = blockIdx.x * 256 + threadIdx.x;
    int4 vv = make_int4(0, 0, 0, 0);
    if (i4 < N4) vv = ((const int4*)count)[i4];
    int s = vv.x + vv.y + vv.z + vv.w;
    int lane = threadIdx.x & 63, w = threadIdx.x >> 6;
    int inc = s;
#pragma unroll
    for (int off = 1; off < 64; off <<= 1) {
        int u = __shfl_up(inc, off);
        if (lane >= off) inc += u;
    }
    if (lane == 63) wt[w] = inc;
    __syncthreads();
    int woff = 0;
    for (int i = 0; i < w; ++i) woff += wt[i];
    int exd = s_boff + woff + inc - s;  // exclusive prefix
    if (i4 < N4) {
        int4 o;
        o.x = exd;
        o.y = exd + vv.x;
        o.z = exd + vv.x + vv.y;
        o.w = exd + vv.x + vv.y + vv.z;
        ((int4*)offs)[i4] = o;
        float4 ad = ((const float4*)a_dst)[i4];
        float4 d0 = make_float4(ad.x, __int_as_float(o.x),
                                ad.y, __int_as_float(o.y));
        float4 d1 = make_float4(ad.z, __int_as_float(o.z),
                                ad.w, __int_as_float(o.w));
        ((float4*)dinfo)[i4 * 2] = d0;
        ((float4*)dinfo)[i4 * 2 + 1] = d1;
    }
}

// ---------- edge pass: 4 edges/thread, no atomics, deterministic CSR slot ----------
__global__ __launch_bounds__(256) void edge_fill(
    const int* __restrict__ ei, const unsigned* __restrict__ erec,
    const float* __restrict__ a_src, const float2* __restrict__ dinfo,
    unsigned* __restrict__ pairs, int E) {
    const int t = threadIdx.x;
    const int base = blockIdx.x * 1024 + t;
    int eidx[4], sn[4], dn[4], rk[4];
    float ae[4];
    bool ok[4];
#pragma unroll
    for (int i = 0; i < 4; ++i) {
        eidx[i] = base + 256 * i;
        ok[i] = eidx[i] < E;
    }
#pragma unroll
    for (int i = 0; i < 4; ++i) {
        sn[i] = ok[i] ? ei[eidx[i]] : 0;
        dn[i] = ok[i] ? ei[E + eidx[i]] : 0;
    }
#pragma unroll
    for (int i = 0; i < 4; ++i) {
        unsigned er = ok[i] ? erec[eidx[i]] : 0u;
        rk[i] = (int)(er & 0xffffu);
        ae[i] = __half2float(__ushort_as_half((unsigned short)(er >> 16)));
    }
    float asv[4];
    float2 di[4];
#pragma unroll
    for (int i = 0; i < 4; ++i) {
        asv[i] = a_src[sn[i]];
        di[i] = dinfo[dn[i]];
    }
#pragma unroll
    for (int i = 0; i < 4; ++i) {
        if (!ok[i]) continue;
        float alpha = asv[i] + di[i].x + ae[i];
        alpha = alpha > 0.0f ? alpha : 0.2f * alpha;
        float ex = __expf(alpha);
        unsigned rec = (unsigned)(unsigned short)sn[i] |
                       ((unsigned)__half_as_ushort(__float2half(ex)) << 16);
        int p = __float_as_int(di[i].y) + rk[i];
        pairs[p] = rec;
    }
}

#define GATHER_EDGE(rec)                                                      \
    {                                                                         \
        unsigned q = hb[(size_t)((rec) & 0xffffu) * 64 + lane];               \
        float exv = __half2float(__ushort_as_half((unsigned short)((rec) >> 16))); \
        a0 += exv * __uint_as_float(q << 16);                                 \
        a1 += exv * __uint_as_float(q & 0xffff0000u);                         \
        sum += exv;                                                           \
    }

// ---------- gather: wave per node; out = sum(ex*h[src])/sum(ex) + bias ----------
__global__ __launch_bounds__(256) void gather_k(
    const int* __restrict__ count, const int* __restrict__ offs,
    const unsigned* __restrict__ pairs, const unsigned* __restrict__ hb,
    const float* __restrict__ bias, float* __restrict__ out, int N) {
    int n = blockIdx.x * 4 + (threadIdx.x >> 6);
    int lane = threadIdx.x & 63;
    if (n >= N) return;
    int cnt = count[n];
    int start = offs[n];
    float a0 = 0.0f, a1 = 0.0f, sum = 0.0f;
    int j = 0;
    int head = (4 - (start & 3)) & 3;
    if (head > cnt) head = cnt;
    for (; j < head; ++j) {
        unsigned r = pairs[start + j];
        GATHER_EDGE(r);
    }
    int nq = (cnt - j) >> 2;
    if (nq > 0) {
        const uint4* pp4 = (const uint4*)(pairs + start + j);
        uint4 cur = pp4[0];
        for (int g = 0; g + 1 < nq; ++g) {
            uint4 nxt = pp4[g + 1];
            unsigned q0 = hb[(size_t)(cur.x & 0xffffu) * 64 + lane];
            unsigned q1 = hb[(size_t)(cur.y & 0xffffu) * 64 + lane];
            unsigned q2 = hb[(size_t)(cur.z & 0xffffu) * 64 + lane];
            unsigned q3 = hb[(size_t)(cur.w & 0xffffu) * 64 + lane];
            float e0 = __half2float(__ushort_as_half((unsigned short)(cur.x >> 16)));
            float e1 = __half2float(__ushort_as_half((unsigned short)(cur.y >> 16)));
            float e2 = __half2float(__ushort_as_half((unsigned short)(cur.z >> 16)));
            float e3 = __half2float(__ushort_as_half((unsigned short)(cur.w >> 16)));
            a0 += e0 * __uint_as_float(q0 << 16);
            a1 += e0 * __uint_as_float(q0 & 0xffff0000u);
            a0 += e1 * __uint_as_float(q1 << 16);
            a1 += e1 * __uint_as_float(q1 & 0xffff0000u);
            a0 += e2 * __uint_as_float(q2 << 16);
            a1 += e2 * __uint_as_float(q2 & 0xffff0000u);
            a0 += e3 * __uint_as_float(q3 << 16);
            a1 += e3 * __uint_as_float(q3 & 0xffff0000u);
            sum += (e0 + e1) + (e2 + e3);
            cur = nxt;
        }
        {
            unsigned q0 = hb[(size_t)(cur.x & 0xffffu) * 64 + lane];
            unsigned q1 = hb[(size_t)(cur.y & 0xffffu) * 64 + lane];
            unsigned q2 = hb[(size_t)(cur.z & 0xffffu) * 64 + lane];
            unsigned q3 = hb[(size_t)(cur.w & 0xffffu) * 64 + lane];
            float e0 = __half2float(__ushort_as_half((unsigned short)(cur.x >> 16)));
            float e1 = __half2float(__ushort_as_half((unsigned short)(cur.y >> 16)));
            float e2 = __half2float(__ushort_as_half((unsigned short)(cur.z >> 16)));
            float e3 = __half2float(__ushort_as_half((unsigned short)(cur.w >> 16)));
            a0 += e0 * __uint_as_float(q0 << 16);
            a1 += e0 * __uint_as_float(q0 & 0xffff0000u);
            a0 += e1 * __uint_as_float(q1 << 16);
            a1 += e1 * __uint_as_float(q1 & 0xffff0000u);
            a0 += e2 * __uint_as_float(q2 << 16);
            a1 += e2 * __uint_as_float(q2 & 0xffff0000u);
            a0 += e3 * __uint_as_float(q3 << 16);
            a1 += e3 * __uint_as_float(q3 & 0xffff0000u);
            sum += (e0 + e1) + (e2 + e3);
        }
        j += nq * 4;
    }
    for (; j < cnt; ++j) {
        unsigned r = pairs[start + j];
        GATHER_EDGE(r);
    }
    float inv = 1.0f / (sum + 1e-16f);
    float2 bv = *(const float2*)&bias[2 * lane];
    float2 o;
    o.x = a0 * inv + bv.x;
    o.y = a1 * inv + bv.y;
    *(float2*)&out[(size_t)n * CCH + 2 * lane] = o;
}

extern "C" void kernel_launch(void* const* d_in, const int* in_sizes, int n_in,
                              void* d_out, int out_size, void* d_ws, size_t ws_size,
                              hipStream_t stream) {
    const float* x        = (const float*)d_in[0];
    const int*   ei       = (const int*)d_in[1];
    const float* ea       = (const float*)d_in[2];
    const float* W        = (const float*)d_in[3];
    const float* W_edge   = (const float*)d_in[4];
    const float* att_src  = (const float*)d_in[5];
    const float* att_dst  = (const float*)d_in[6];
    const float* att_edge = (const float*)d_in[7];
    const float* bias     = (const float*)d_in[8];
    float* out = (float*)d_out;

    const int N = in_sizes[0] / DIN;   // 40000
    const int E = in_sizes[2] / EDIM;  // 640000
    const int N4 = N / 4;              // 10000
    const int NB = (N4 + 255) / 256;   // 40 scan blocks

    // workspace layout — total 16,320,160 B (< 16 MiB), 16-B aligned segments
    char* ws = (char*)d_ws;
    unsigned* hb    = (unsigned*)ws;                          // N*64 u32  10.24MB
    unsigned* pairs = (unsigned*)(ws + (size_t)N * 64 * 4);   // E u32      2.56MB
    unsigned* erec  = pairs + E;                              // E u32      2.56MB
    float*  a_src = (float*)(erec + E);                       // N f
    float*  a_dst = a_src + N;                                // N f
    float2* dinfo = (float2*)(a_dst + N);                     // N float2
    int*    count = (int*)(dinfo + N);                        // N i
    int*    offs  = count + N;                                // N i
    int*    bsum  = offs + N;                                 // NB i

    hipMemsetAsync(count, 0, (size_t)N * sizeof(int), stream);

    gemm_h<<<N / 64, 256, 0, stream>>>(x, W, att_src, att_dst, W_edge, att_edge,
                                       ei, ea, hb, a_src, a_dst, erec,
                                       count, N, E);
    scan_part<<<NB, 256, 0, stream>>>(count, bsum, N4);
    scan_apply<<<NB, 256, 0, stream>>>(count, bsum, a_dst, offs, dinfo, N4);
    edge_fill<<<(E + 1023) / 1024, 256, 0, stream>>>(ei, erec, a_src, dinfo,
                                                     pairs, E);
    gather_k<<<(N + 3) / 4, 256, 0, stream>>>(count, offs, pairs, hb, bias, out, N);
}

// Round 4
// 230.653 us; speedup vs baseline: 1.1139x; 1.0358x over previous
//
#include <hip/hip_runtime.h>
#include <hip/hip_bf16.h>
#include <hip/hip_fp16.h>

// EGATConv: GATConv(heads=1) with edge features. N=40000, E=640000,
// DIN=C=128, EDIM=32, fp32 in/out.
//
// Round-9 structure (R8 + grid-role split):
//  - R8 post-mortem: ea stream fused into gemm_h ran AFTER the GEMM epilogue
//    at 625-block grid (2.4 blocks/CU, 20% occupancy) -> 1.25 TB/s, 71 us.
//    The stream was serialized, not hidden.
//  - R9: one kernel, 1875 blocks. Blocks <625: GEMM role (MFMA bf16x2,
//    unchanged). Blocks >=625: streamer role, 512 ea rows/block -> fp16
//    a_edge in erec hi half. count/rank atomic loop grid-strides all blocks.
//    CU co-schedules ~2-3 GEMM + ~2-3 streamer blocks (LDS 32KB -> 5/CU);
//    streamers saturate HBM while GEMM waves sit at barriers.
//  - erec[e] u32 = rank u16 (lo) | fp16 a_edge (hi); ws total 16.32MB < 16MiB.
//  - rest identical: scan, no-atomic edge_fill CSR placement, wave-per-node
//    gather, bf16 h, fp16 ex records.

#define DIN 128
#define CCH 128
#define EDIM 32
#define LDK 40  // padded k stride in ushorts (80 B rows, 16-B aligned frags)

typedef __attribute__((ext_vector_type(8))) short short8v;
typedef __attribute__((ext_vector_type(4))) float f32x4;

__device__ __forceinline__ unsigned short f2b(float v) {
    __hip_bfloat16 b = __float2bfloat16(v);
    return *(unsigned short*)&b;
}
__device__ __forceinline__ float b2f(unsigned short u) {
    return __uint_as_float((unsigned)u << 16);
}
__device__ __forceinline__ unsigned pack_bf2(float a, float b) {
    return (unsigned)f2b(a) | ((unsigned)f2b(b) << 16);
}

// ---------- fused: GEMM role (h, logits) + streamer role (a_edge) + count ----------
__global__ __launch_bounds__(256, 4) void gemm_h(
    const float* __restrict__ x, const float* __restrict__ W,
    const float* __restrict__ att_src, const float* __restrict__ att_dst,
    const float* __restrict__ W_edge, const float* __restrict__ att_edge,
    const int* __restrict__ ei, const float* __restrict__ ea,
    unsigned* __restrict__ hb, float* __restrict__ a_src,
    float* __restrict__ a_dst, unsigned* __restrict__ erec,
    int* __restrict__ count, int GB, int N, int E) {
    __shared__ unsigned short xs_h[64 * LDK];   // x quarter, hi plane  [r][k]
    __shared__ unsigned short xs_l[64 * LDK];   // lo plane
    __shared__ unsigned short wt_h[128 * LDK];  // W^T quarter, hi      [c][k]
    __shared__ unsigned short wt_l[128 * LDK];  // lo plane
    __shared__ float vpart[8][EDIM];
    __shared__ float vl[EDIM];

    const int t = threadIdx.x;
    const int bid = blockIdx.x;

    // fused degree count + per-edge rank (all blocks participate)
    {
        const int* eid = ei + E;
        const int stride = gridDim.x * 256;
        for (int e = bid * 256 + t; e < E; e += stride) {
            int r = atomicAdd(&count[eid[e]], 1);
            ((unsigned short*)&erec[e])[0] = (unsigned short)r;  // lo half
        }
    }

    if (bid >= GB) {
        // ---------------- streamer role: a_edge for 512 edges ----------------
        {
            int j = t & 31, seg = t >> 5;  // 8 segments x 16 k
            const float* wr = W_edge + j * CCH + seg * 16;
            const float* ar = att_edge + seg * 16;
            float p = 0.0f;
#pragma unroll
            for (int k = 0; k < 16; ++k) p += wr[k] * ar[k];
            vpart[seg][j] = p;
        }
        __syncthreads();
        if (t < EDIM) {
            float s = 0.0f;
#pragma unroll
            for (int i = 0; i < 8; ++i) s += vpart[i][t];
            vl[t] = s;
        }
        __syncthreads();
        float vlr[EDIM];
#pragma unroll
        for (int j = 0; j < EDIM; ++j) vlr[j] = vl[j];

        const float4* ea4 = (const float4*)ea;
        const int e0 = (bid - GB) * 512 + t;
#pragma unroll
        for (int i = 0; i < 2; ++i) {
            int e = e0 + 256 * i;
            if (e < E) {
                float s = 0.0f;
#pragma unroll
                for (int j = 0; j < 8; ++j) {
                    float4 v = ea4[(size_t)e * 8 + j];
                    s += v.x * vlr[4 * j] + v.y * vlr[4 * j + 1] +
                         v.z * vlr[4 * j + 2] + v.w * vlr[4 * j + 3];
                }
                ((unsigned short*)&erec[e])[1] =
                    __half_as_ushort(__float2half(s));  // hi half
            }
        }
        return;
    }

    // ---------------- GEMM role ----------------
    const int ln = t & 63;
    const int wv = t >> 6;
    const int lr = ln & 15;  // B col (node row) / A row (channel) in fragment
    const int lk = ln >> 4;  // k-group
    const int row0 = bid * 64;

    f32x4 acc[8];
#pragma unroll
    for (int cf = 0; cf < 8; ++cf) acc[cf] = (f32x4)(0.0f);

    const float4* x4 = (const float4*)x;
    const float4* W4 = (const float4*)W;

    for (int q = 0; q < 4; ++q) {  // K quarters of 32
        __syncthreads();
        // stage x quarter: 64 rows x 32 k, fp32 -> bf16 hi/lo
#pragma unroll
        for (int i = 0; i < 2; ++i) {
            int j4 = t + 256 * i;
            int r = j4 >> 3;
            int f4 = j4 & 7;
            float4 v = x4[(size_t)(row0 + r) * 32 + q * 8 + f4];
            float vv[4] = {v.x, v.y, v.z, v.w};
            unsigned short h[4], l[4];
#pragma unroll
            for (int m = 0; m < 4; ++m) {
                h[m] = f2b(vv[m]);
                l[m] = f2b(vv[m] - b2f(h[m]));
            }
            uint2 uh = make_uint2((unsigned)h[0] | ((unsigned)h[1] << 16),
                                  (unsigned)h[2] | ((unsigned)h[3] << 16));
            uint2 ul = make_uint2((unsigned)l[0] | ((unsigned)l[1] << 16),
                                  (unsigned)l[2] | ((unsigned)l[3] << 16));
            *(uint2*)&xs_h[r * LDK + f4 * 4] = uh;
            *(uint2*)&xs_l[r * LDK + f4 * 4] = ul;
        }
        // stage W^T quarter: 32 k x 128 c, transposed to [c][k] hi/lo
        {
            int kt = t >> 5;   // k base kt*4
            int ct = t & 31;   // c base ct*4
            float w4[4][4];
#pragma unroll
            for (int i = 0; i < 4; ++i) {
                float4 v = W4[(size_t)(q * 32 + kt * 4 + i) * 32 + ct];
                w4[i][0] = v.x; w4[i][1] = v.y; w4[i][2] = v.z; w4[i][3] = v.w;
            }
#pragma unroll
            for (int cc = 0; cc < 4; ++cc) {
                unsigned short h[4], l[4];
#pragma unroll
                for (int i = 0; i < 4; ++i) {
                    h[i] = f2b(w4[i][cc]);
                    l[i] = f2b(w4[i][cc] - b2f(h[i]));
                }
                uint2 uh = make_uint2((unsigned)h[0] | ((unsigned)h[1] << 16),
                                      (unsigned)h[2] | ((unsigned)h[3] << 16));
                uint2 ul = make_uint2((unsigned)l[0] | ((unsigned)l[1] << 16),
                                      (unsigned)l[2] | ((unsigned)l[3] << 16));
                int c = ct * 4 + cc;
                *(uint2*)&wt_h[c * LDK + kt * 4] = uh;
                *(uint2*)&wt_l[c * LDK + kt * 4] = ul;
            }
        }
        __syncthreads();

        // one K=32 MFMA step per quarter
        short8v bh = *(const short8v*)&xs_h[(wv * 16 + lr) * LDK + lk * 8];
        short8v bl = *(const short8v*)&xs_l[(wv * 16 + lr) * LDK + lk * 8];
#pragma unroll
        for (int cf = 0; cf < 8; ++cf) {
            short8v ah = *(const short8v*)&wt_h[(cf * 16 + lr) * LDK + lk * 8];
            short8v al = *(const short8v*)&wt_l[(cf * 16 + lr) * LDK + lk * 8];
            acc[cf] = __builtin_amdgcn_mfma_f32_16x16x32_bf16(ah, bh, acc[cf], 0, 0, 0);
            acc[cf] = __builtin_amdgcn_mfma_f32_16x16x32_bf16(ah, bl, acc[cf], 0, 0, 0);
            acc[cf] = __builtin_amdgcn_mfma_f32_16x16x32_bf16(al, bh, acc[cf], 0, 0, 0);
        }
    }

    // outputs: lane holds h[row][c..c+3] for row=row0+wv*16+lr, c=cf*16+lk*4
    {
        const int row = row0 + wv * 16 + lr;
        float ps = 0.0f, pd = 0.0f;
#pragma unroll
        for (int cf = 0; cf < 8; ++cf) {
            int c0 = cf * 16 + lk * 4;
            float4 as4 = *(const float4*)&att_src[c0];
            float4 ad4 = *(const float4*)&att_dst[c0];
            ps += acc[cf][0] * as4.x + acc[cf][1] * as4.y +
                  acc[cf][2] * as4.z + acc[cf][3] * as4.w;
            pd += acc[cf][0] * ad4.x + acc[cf][1] * ad4.y +
                  acc[cf][2] * ad4.z + acc[cf][3] * ad4.w;
            uint2 u = make_uint2(pack_bf2(acc[cf][0], acc[cf][1]),
                                 pack_bf2(acc[cf][2], acc[cf][3]));
            *(uint2*)&hb[(size_t)row * 64 + cf * 8 + lk * 2] = u;
        }
        ps += __shfl_xor(ps, 16);
        ps += __shfl_xor(ps, 32);
        pd += __shfl_xor(pd, 16);
        pd += __shfl_xor(pd, 32);
        if (ln < 16) {
            a_src[row0 + wv * 16 + ln] = ps;
            a_dst[row0 + wv * 16 + ln] = pd;
        }
    }
}

// ---------- scan phase 1: per-block sums of count (int4) ----------
__global__ __launch_bounds__(256) void scan_part(const int* __restrict__ count,
                                                 int* __restrict__ bsum, int N4) {
    int i4 = blockIdx.x * 256 + threadIdx.x;
    int s = 0;
    if (i4 < N4) {
        int4 vv = ((const int4*)count)[i4];
        s = vv.x + vv.y + vv.z + vv.w;
    }
#pragma unroll
    for (int off = 32; off; off >>= 1) s += __shfl_down(s, off);
    __shared__ int wsum[4];
    if ((threadIdx.x & 63) == 0) wsum[threadIdx.x >> 6] = s;
    __syncthreads();
    if (threadIdx.x == 0)
        bsum[blockIdx.x] = wsum[0] + wsum[1] + wsum[2] + wsum[3];
}

// ---------- scan phase 2: exclusive offs + dinfo = {a_dst, bits(offs)} ----------
__global__ __launch_bounds__(256) void scan_apply(
    const int* __restrict__ count, const int* __restrict__ bsum,
    const float* __restrict__ a_dst, int* __restrict__ offs,
    float2* __restrict__ dinfo, int N4) {
    __shared__ int s_boff;
    __shared__ int wt[4];
    if (threadIdx.x == 0) {
        int s = 0;
        for (int i = 0; i < (int)blockIdx.x; ++i) s += bsum[i];
        s_boff = s;
    }
    int i4 = blockIdx.x * 256 + threadIdx.x;
    int4 vv = make_int4(0, 0, 0, 0);
    if (i4 < N4) vv = ((const int4*)count)[i4];
    int s = vv.x + vv.y + vv.z + vv.w;
    int lane = threadIdx.x & 63, w = threadIdx.x >> 6;
    int inc = s;
#pragma unroll
    for (int off = 1; off < 64; off <<= 1) {
        int u = __shfl_up(inc, off);
        if (lane >= off) inc += u;
    }
    if (lane == 63) wt[w] = inc;
    __syncthreads();
    int woff = 0;
    for (int i = 0; i < w; ++i) woff += wt[i];
    int exd = s_boff + woff + inc - s;  // exclusive prefix
    if (i4 < N4) {
        int4 o;
        o.x = exd;
        o.y = exd + vv.x;
        o.z = exd + vv.x + vv.y;
        o.w = exd + vv.x + vv.y + vv.z;
        ((int4*)offs)[i4] = o;
        float4 ad = ((const float4*)a_dst)[i4];
        float4 d0 = make_float4(ad.x, __int_as_float(o.x),
                                ad.y, __int_as_float(o.y));
        float4 d1 = make_float4(ad.z, __int_as_float(o.z),
                                ad.w, __int_as_float(o.w));
        ((float4*)dinfo)[i4 * 2] = d0;
        ((float4*)dinfo)[i4 * 2 + 1] = d1;
    }
}

// ---------- edge pass: 4 edges/thread, no atomics, deterministic CSR slot ----------
__global__ __launch_bounds__(256) void edge_fill(
    const int* __restrict__ ei, const unsigned* __restrict__ erec,
    const float* __restrict__ a_src, const float2* __restrict__ dinfo,
    unsigned* __restrict__ pairs, int E) {
    const int t = threadIdx.x;
    const int base = blockIdx.x * 1024 + t;
    int eidx[4], sn[4], dn[4], rk[4];
    float ae[4];
    bool ok[4];
#pragma unroll
    for (int i = 0; i < 4; ++i) {
        eidx[i] = base + 256 * i;
        ok[i] = eidx[i] < E;
    }
#pragma unroll
    for (int i = 0; i < 4; ++i) {
        sn[i] = ok[i] ? ei[eidx[i]] : 0;
        dn[i] = ok[i] ? ei[E + eidx[i]] : 0;
    }
#pragma unroll
    for (int i = 0; i < 4; ++i) {
        unsigned er = ok[i] ? erec[eidx[i]] : 0u;
        rk[i] = (int)(er & 0xffffu);
        ae[i] = __half2float(__ushort_as_half((unsigned short)(er >> 16)));
    }
    float asv[4];
    float2 di[4];
#pragma unroll
    for (int i = 0; i < 4; ++i) {
        asv[i] = a_src[sn[i]];
        di[i] = dinfo[dn[i]];
    }
#pragma unroll
    for (int i = 0; i < 4; ++i) {
        if (!ok[i]) continue;
        float alpha = asv[i] + di[i].x + ae[i];
        alpha = alpha > 0.0f ? alpha : 0.2f * alpha;
        float ex = __expf(alpha);
        unsigned rec = (unsigned)(unsigned short)sn[i] |
                       ((unsigned)__half_as_ushort(__float2half(ex)) << 16);
        int p = __float_as_int(di[i].y) + rk[i];
        pairs[p] = rec;
    }
}

#define GATHER_EDGE(rec)                                                      \
    {                                                                         \
        unsigned q = hb[(size_t)((rec) & 0xffffu) * 64 + lane];               \
        float exv = __half2float(__ushort_as_half((unsigned short)((rec) >> 16))); \
        a0 += exv * __uint_as_float(q << 16);                                 \
        a1 += exv * __uint_as_float(q & 0xffff0000u);                         \
        sum += exv;                                                           \
    }

// ---------- gather: wave per node; out = sum(ex*h[src])/sum(ex) + bias ----------
__global__ __launch_bounds__(256) void gather_k(
    const int* __restrict__ count, const int* __restrict__ offs,
    const unsigned* __restrict__ pairs, const unsigned* __restrict__ hb,
    const float* __restrict__ bias, float* __restrict__ out, int N) {
    int n = blockIdx.x * 4 + (threadIdx.x >> 6);
    int lane = threadIdx.x & 63;
    if (n >= N) return;
    int cnt = count[n];
    int start = offs[n];
    float a0 = 0.0f, a1 = 0.0f, sum = 0.0f;
    int j = 0;
    int head = (4 - (start & 3)) & 3;
    if (head > cnt) head = cnt;
    for (; j < head; ++j) {
        unsigned r = pairs[start + j];
        GATHER_EDGE(r);
    }
    int nq = (cnt - j) >> 2;
    if (nq > 0) {
        const uint4* pp4 = (const uint4*)(pairs + start + j);
        uint4 cur = pp4[0];
        for (int g = 0; g + 1 < nq; ++g) {
            uint4 nxt = pp4[g + 1];
            unsigned q0 = hb[(size_t)(cur.x & 0xffffu) * 64 + lane];
            unsigned q1 = hb[(size_t)(cur.y & 0xffffu) * 64 + lane];
            unsigned q2 = hb[(size_t)(cur.z & 0xffffu) * 64 + lane];
            unsigned q3 = hb[(size_t)(cur.w & 0xffffu) * 64 + lane];
            float e0 = __half2float(__ushort_as_half((unsigned short)(cur.x >> 16)));
            float e1 = __half2float(__ushort_as_half((unsigned short)(cur.y >> 16)));
            float e2 = __half2float(__ushort_as_half((unsigned short)(cur.z >> 16)));
            float e3 = __half2float(__ushort_as_half((unsigned short)(cur.w >> 16)));
            a0 += e0 * __uint_as_float(q0 << 16);
            a1 += e0 * __uint_as_float(q0 & 0xffff0000u);
            a0 += e1 * __uint_as_float(q1 << 16);
            a1 += e1 * __uint_as_float(q1 & 0xffff0000u);
            a0 += e2 * __uint_as_float(q2 << 16);
            a1 += e2 * __uint_as_float(q2 & 0xffff0000u);
            a0 += e3 * __uint_as_float(q3 << 16);
            a1 += e3 * __uint_as_float(q3 & 0xffff0000u);
            sum += (e0 + e1) + (e2 + e3);
            cur = nxt;
        }
        {
            unsigned q0 = hb[(size_t)(cur.x & 0xffffu) * 64 + lane];
            unsigned q1 = hb[(size_t)(cur.y & 0xffffu) * 64 + lane];
            unsigned q2 = hb[(size_t)(cur.z & 0xffffu) * 64 + lane];
            unsigned q3 = hb[(size_t)(cur.w & 0xffffu) * 64 + lane];
            float e0 = __half2float(__ushort_as_half((unsigned short)(cur.x >> 16)));
            float e1 = __half2float(__ushort_as_half((unsigned short)(cur.y >> 16)));
            float e2 = __half2float(__ushort_as_half((unsigned short)(cur.z >> 16)));
            float e3 = __half2float(__ushort_as_half((unsigned short)(cur.w >> 16)));
            a0 += e0 * __uint_as_float(q0 << 16);
            a1 += e0 * __uint_as_float(q0 & 0xffff0000u);
            a0 += e1 * __uint_as_float(q1 << 16);
            a1 += e1 * __uint_as_float(q1 & 0xffff0000u);
            a0 += e2 * __uint_as_float(q2 << 16);
            a1 += e2 * __uint_as_float(q2 & 0xffff0000u);
            a0 += e3 * __uint_as_float(q3 << 16);
            a1 += e3 * __uint_as_float(q3 & 0xffff0000u);
            sum += (e0 + e1) + (e2 + e3);
        }
        j += nq * 4;
    }
    for (; j < cnt; ++j) {
        unsigned r = pairs[start + j];
        GATHER_EDGE(r);
    }
    float inv = 1.0f / (sum + 1e-16f);
    float2 bv = *(const float2*)&bias[2 * lane];
    float2 o;
    o.x = a0 * inv + bv.x;
    o.y = a1 * inv + bv.y;
    *(float2*)&out[(size_t)n * CCH + 2 * lane] = o;
}

extern "C" void kernel_launch(void* const* d_in, const int* in_sizes, int n_in,
                              void* d_out, int out_size, void* d_ws, size_t ws_size,
                              hipStream_t stream) {
    const float* x        = (const float*)d_in[0];
    const int*   ei       = (const int*)d_in[1];
    const float* ea       = (const float*)d_in[2];
    const float* W        = (const float*)d_in[3];
    const float* W_edge   = (const float*)d_in[4];
    const float* att_src  = (const float*)d_in[5];
    const float* att_dst  = (const float*)d_in[6];
    const float* att_edge = (const float*)d_in[7];
    const float* bias     = (const float*)d_in[8];
    float* out = (float*)d_out;

    const int N = in_sizes[0] / DIN;   // 40000
    const int E = in_sizes[2] / EDIM;  // 640000
    const int N4 = N / 4;              // 10000
    const int NB = (N4 + 255) / 256;   // 40 scan blocks
    const int GB = N / 64;             // 625 GEMM-role blocks
    const int SB = (E + 511) / 512;    // 1250 streamer-role blocks

    // workspace layout — total 16,320,160 B (< 16 MiB), 16-B aligned segments
    char* ws = (char*)d_ws;
    unsigned* hb    = (unsigned*)ws;                          // N*64 u32  10.24MB
    unsigned* pairs = (unsigned*)(ws + (size_t)N * 64 * 4);   // E u32      2.56MB
    unsigned* erec  = pairs + E;                              // E u32      2.56MB
    float*  a_src = (float*)(erec + E);                       // N f
    float*  a_dst = a_src + N;                                // N f
    float2* dinfo = (float2*)(a_dst + N);                     // N float2
    int*    count = (int*)(dinfo + N);                        // N i
    int*    offs  = count + N;                                // N i
    int*    bsum  = offs + N;                                 // NB i

    hipMemsetAsync(count, 0, (size_t)N * sizeof(int), stream);

    gemm_h<<<GB + SB, 256, 0, stream>>>(x, W, att_src, att_dst, W_edge, att_edge,
                                        ei, ea, hb, a_src, a_dst, erec,
                                        count, GB, N, E);
    scan_part<<<NB, 256, 0, stream>>>(count, bsum, N4);
    scan_apply<<<NB, 256, 0, stream>>>(count, bsum, a_dst, offs, dinfo, N4);
    edge_fill<<<(E + 1023) / 1024, 256, 0, stream>>>(ei, erec, a_src, dinfo,
                                                     pairs, E);
    gather_k<<<(N + 3) / 4, 256, 0, stream>>>(count, offs, pairs, hb, bias, out, N);
}